// Round 5
// baseline (955.993 us; speedup 1.0000x reference)
//
#include <hip/hip_runtime.h>
#include <stdint.h>
#include <stddef.h>

// Problem constants (B=2, S=2048, D_MODEL=1024, H=16, Dh=64).
// I/O dtype: fp32 (per reference). Internal compute: bf16 MFMA + fp32 accum.
#define D_MODEL 1024
#define NHEADS  16
#define HDIM    64
#define BB      2
#define SSEQ    2048

using bf16x8 = __attribute__((ext_vector_type(8))) short;  // 8 bf16 (4 VGPRs)
using f32x4  = __attribute__((ext_vector_type(4))) float;  // MFMA accumulator
using s16x4  = __attribute__((ext_vector_type(4))) short;

static __device__ __forceinline__ float b2f(short s) {
  union { float f; unsigned u; } v;
  v.u = ((unsigned)(unsigned short)s) << 16;
  return v.f;
}
static __device__ __forceinline__ short f2b(float f) {
  union { float f; unsigned u; } v;
  v.f = f;
  unsigned r = v.u + 0x7fffu + ((v.u >> 16) & 1u);  // RNE
  return (short)(r >> 16);
}

// async global->LDS, 16B per lane; LDS dest = wave-uniform base + lane*16
static __device__ __forceinline__ void gload16(const void* g, void* l) {
  __builtin_amdgcn_global_load_lds(
      (const __attribute__((address_space(1))) unsigned int*)g,
      (__attribute__((address_space(3))) unsigned int*)l, 16, 0, 0);
}

// ---------------------------------------------------------------------------
// fp32 -> bf16 conversion (grid-stride, float4 loads, 8B stores)
// ---------------------------------------------------------------------------
__global__ __launch_bounds__(256) void k_cvt(const float* __restrict__ src,
                                             short* __restrict__ dst, int n4) {
  int i = blockIdx.x * blockDim.x + threadIdx.x;
  const int stride = gridDim.x * blockDim.x;
  for (; i < n4; i += stride) {
    const float4 v = ((const float4*)src)[i];
    s16x4 o;
    o[0] = f2b(v.x); o[1] = f2b(v.y); o[2] = f2b(v.z); o[3] = f2b(v.w);
    ((s16x4*)dst)[i] = o;
  }
}

// ---------------------------------------------------------------------------
// C[M,N] = A[M,K] @ W[N,K]^T   (bf16 in, fp32 accum; out bf16 or fp32)
// 128x128 tile, BK=32, 256 threads (4 waves in 2x2), m97-style staging.
// ---------------------------------------------------------------------------
template <bool F32OUT>
static __device__ __forceinline__ void gemm_bt_dev(
    const short* __restrict__ A, const short* __restrict__ W, void* __restrict__ Cv,
    int N, int K) {
  __shared__ short sA[128 * 32];
  __shared__ short sB[128 * 32];

  const int t  = threadIdx.x;
  const int l  = t & 63;
  const int w  = t >> 6;
  const int wm = w >> 1, wn = w & 1;
  const int g  = l >> 4, lr = l & 15;
  const int m0 = blockIdx.y * 128;
  const int n0 = blockIdx.x * 128;

  f32x4 acc[4][4];
#pragma unroll
  for (int i = 0; i < 4; ++i)
#pragma unroll
    for (int j = 0; j < 4; ++j) {
      acc[i][j][0] = 0.f; acc[i][j][1] = 0.f;
      acc[i][j][2] = 0.f; acc[i][j][3] = 0.f;
    }

  // staging: chunk t (16B) = tile row t/4, cols (t%4)*8 .. +8; thread t owns
  // chunks t and t+256; LDS offset of chunk i is i*16B (row-major [128][32]).
  const int r0 = t >> 2;
  const int c0 = (t & 3) * 8;
  const short* ga0 = A + (size_t)(m0 + r0) * K + c0;
  const short* ga1 = A + (size_t)(m0 + 64 + r0) * K + c0;
  const short* gb0 = W + (size_t)(n0 + r0) * K + c0;
  const short* gb1 = W + (size_t)(n0 + 64 + r0) * K + c0;
  short* la0 = &sA[(t & ~63) * 8];
  short* la1 = la0 + 256 * 8;
  short* lb0 = &sB[(t & ~63) * 8];
  short* lb1 = lb0 + 256 * 8;

  for (int k0 = 0; k0 < K; k0 += 32) {
    __syncthreads();  // WAR: previous iter's fragment reads done
    gload16(ga0 + k0, la0);
    gload16(ga1 + k0, la1);
    gload16(gb0 + k0, lb0);
    gload16(gb1 + k0, lb1);
    __syncthreads();  // drains vmcnt: staged tile visible

    bf16x8 af[4], bfr[4];
#pragma unroll
    for (int i = 0; i < 4; ++i)
      af[i] = *(const bf16x8*)&sA[(wm * 64 + i * 16 + lr) * 32 + g * 8];
#pragma unroll
    for (int i = 0; i < 4; ++i)
      bfr[i] = *(const bf16x8*)&sB[(wn * 64 + i * 16 + lr) * 32 + g * 8];
#pragma unroll
    for (int i = 0; i < 4; ++i)
#pragma unroll
      for (int j = 0; j < 4; ++j)
        acc[i][j] = __builtin_amdgcn_mfma_f32_16x16x32_bf16(af[i], bfr[j],
                                                            acc[i][j], 0, 0, 0);
  }

  // epilogue: D row=(lane>>4)*4+reg, col=lane&15  [verified C/D layout]
#pragma unroll
  for (int i = 0; i < 4; ++i)
#pragma unroll
    for (int j = 0; j < 4; ++j)
#pragma unroll
      for (int rr = 0; rr < 4; ++rr) {
        const int row = m0 + wm * 64 + i * 16 + g * 4 + rr;
        const int col = n0 + wn * 64 + j * 16 + lr;
        if (F32OUT)
          ((float*)Cv)[(size_t)row * N + col] = acc[i][j][rr];
        else
          ((short*)Cv)[(size_t)row * N + col] = f2b(acc[i][j][rr]);
      }
}

__global__ __launch_bounds__(256) void k_gemm_f32out(
    const short* __restrict__ A, const short* __restrict__ W,
    float* __restrict__ C, int N, int K) {
  gemm_bt_dev<true>(A, W, C, N, K);
}

__global__ __launch_bounds__(256) void k_gemm_qkv(
    const short* __restrict__ q, const short* __restrict__ k,
    const short* __restrict__ v, const short* __restrict__ wq,
    const short* __restrict__ wk, const short* __restrict__ wv,
    short* __restrict__ Qb, short* __restrict__ Kb, short* __restrict__ Vb) {
  const short *A, *W;
  short* C;
  if (blockIdx.z == 0)      { A = q; W = wq; C = Qb; }
  else if (blockIdx.z == 1) { A = k; W = wk; C = Kb; }
  else                      { A = v; W = wv; C = Vb; }
  gemm_bt_dev<false>(A, W, C, D_MODEL, D_MODEL);
}

// ---------------------------------------------------------------------------
// V[b,s,h*64+d] -> Vt[b,h,d,s]  (64x64 LDS tiles, pad 66 to spread banks)
// ---------------------------------------------------------------------------
__global__ __launch_bounds__(256) void k_transpose_v(
    const short* __restrict__ Vb, short* __restrict__ Vt) {
  __shared__ short tile[64][66];
  const int bh = blockIdx.x;            // b*16+h
  const int b = bh >> 4, h = bh & 15;
  const int s0 = blockIdx.y * 64;
  const int t = threadIdx.x;
#pragma unroll
  for (int i = 0; i < 16; ++i) {
    int e = t + i * 256;
    int si = e >> 6, dj = e & 63;
    tile[si][dj] = Vb[((size_t)b * SSEQ + s0 + si) * D_MODEL + h * HDIM + dj];
  }
  __syncthreads();
#pragma unroll
  for (int i = 0; i < 16; ++i) {
    int e = t + i * 256;
    int dj = e >> 6, si = e & 63;
    Vt[((size_t)bh * HDIM + dj) * SSEQ + s0 + si] = tile[si][dj];
  }
}

// ---------------------------------------------------------------------------
// Fused attention, round-5 REWRITE: two-pass register-resident, NO S tile.
// Evidence: r1 (2x occupancy) and r4 (fewer sweeps, batched loads, XCD
// swizzle) both ~null -> the S-in-LDS + barrier-sweep skeleton itself is the
// limiter. New structure per block = (b,h, 16 q-rows), 256 threads (4 waves),
// wave w owns keys [w*512, w*512+512):
//   pass 1: QK^T in registers, per-lane online (m,l); 16-lane shfl combine;
//           4-wave combine via 512 B LDS table (1 barrier).
//   pass 2: recompute QK^T (MFMA was 4% util - recompute is free), write
//           P fp32 straight from accumulators (coalesced dword stores),
//           f2b -> 1.25 KB per-wave ptile -> PV MFMA with Vt (B-operand).
//   O: per-wave partials over full d=64; 16 KB LDS reduce (1 barrier).
// LDS 22 KB (was 68.5), barriers 2 (was 3 + phase gates), zero S sweeps.
// ---------------------------------------------------------------------------
__global__ __launch_bounds__(256) void k_attn(
    const short* __restrict__ Qb, const short* __restrict__ Kb,
    const short* __restrict__ Vt, float* __restrict__ attnO,
    short* __restrict__ ctx) {
  __shared__ __attribute__((aligned(16))) short ptile[4][16][40];  // 5 KB
  __shared__ float wmx[4][16];                                     // 256 B
  __shared__ float wls[4][16];                                     // 256 B
  __shared__ f32x4 red[4][4][64];                                  // 16 KB

  const int t = threadIdx.x;
  const int l = t & 63, w = t >> 6;   // 4 waves
  const int g = l >> 4, lr = l & 15;
  // XCD-chunked bijective swizzle (4096 = 8*512): XCD x runs ids x*512..+511
  const int orig = blockIdx.x;
  const int id = (orig & 7) * 512 + (orig >> 3);
  const int q0 = (id & 127) * 16;
  const int bh = id >> 7;             // 0..31
  const int b = bh >> 4, h = bh & 15;

  // Q fragments (A-operand): lane holds Q[q0+lr][g*8 .. +8] (+32 for step 2)
  const size_t qoff = ((size_t)b * SSEQ + q0 + lr) * D_MODEL + h * HDIM;
  const bf16x8 aq0 = *(const bf16x8*)&Qb[qoff + g * 8];
  const bf16x8 aq1 = *(const bf16x8*)&Qb[qoff + 32 + g * 8];

  const short* Kh = Kb + (size_t)b * SSEQ * D_MODEL + h * HDIM;
  const short* Vh = Vt + (size_t)bh * HDIM * SSEQ;
  const int kbase = w * 512;          // this wave's key range

  // ---- pass 1: online (m,l) across the wave's 512 keys ----
  float pm[4], pl[4];
#pragma unroll
  for (int rr = 0; rr < 4; ++rr) { pm[rr] = -1e30f; pl[rr] = 0.f; }

  for (int st = 0; st < 16; ++st) {
    const int n0 = kbase + st * 32;
    const short* kr0 = Kh + (size_t)(n0 + lr) * D_MODEL;
    const short* kr1 = Kh + (size_t)(n0 + 16 + lr) * D_MODEL;
    const bf16x8 ka0 = *(const bf16x8*)&kr0[g * 8];
    const bf16x8 ka1 = *(const bf16x8*)&kr0[32 + g * 8];
    const bf16x8 kb0 = *(const bf16x8*)&kr1[g * 8];
    const bf16x8 kb1 = *(const bf16x8*)&kr1[32 + g * 8];
    f32x4 sA, sB;
    sA[0] = 0.f; sA[1] = 0.f; sA[2] = 0.f; sA[3] = 0.f;
    sB[0] = 0.f; sB[1] = 0.f; sB[2] = 0.f; sB[3] = 0.f;
    sA = __builtin_amdgcn_mfma_f32_16x16x32_bf16(aq0, ka0, sA, 0, 0, 0);
    sA = __builtin_amdgcn_mfma_f32_16x16x32_bf16(aq1, ka1, sA, 0, 0, 0);
    sB = __builtin_amdgcn_mfma_f32_16x16x32_bf16(aq0, kb0, sB, 0, 0, 0);
    sB = __builtin_amdgcn_mfma_f32_16x16x32_bf16(aq1, kb1, sB, 0, 0, 0);
#pragma unroll
    for (int rr = 0; rr < 4; ++rr) {
      const float s1 = sA[rr] * 0.125f;
      const float s2 = sB[rr] * 0.125f;
      const float nm = fmaxf(pm[rr], fmaxf(s1, s2));
      pl[rr] = pl[rr] * __expf(pm[rr] - nm) + __expf(s1 - nm) + __expf(s2 - nm);
      pm[rr] = nm;
    }
  }
  // combine across the 16 lanes (lr) of each g-group (rows g*4..g*4+3)
#pragma unroll
  for (int mask = 1; mask < 16; mask <<= 1) {
#pragma unroll
    for (int rr = 0; rr < 4; ++rr) {
      const float om = __shfl_xor(pm[rr], mask, 64);
      const float ol = __shfl_xor(pl[rr], mask, 64);
      const float nm = fmaxf(pm[rr], om);
      pl[rr] = pl[rr] * __expf(pm[rr] - nm) + ol * __expf(om - nm);
      pm[rr] = nm;
    }
  }
  if (lr == 0) {
#pragma unroll
    for (int rr = 0; rr < 4; ++rr) {
      wmx[w][g * 4 + rr] = pm[rr];
      wls[w][g * 4 + rr] = pl[rr];
    }
  }
  __syncthreads();

  // combine across the 4 waves -> exact per-row M, 1/L
  float M[4], inv[4];
#pragma unroll
  for (int rr = 0; rr < 4; ++rr) {
    const int row = g * 4 + rr;
    const float m0 = wmx[0][row], m1 = wmx[1][row];
    const float m2 = wmx[2][row], m3 = wmx[3][row];
    const float Mv = fmaxf(fmaxf(m0, m1), fmaxf(m2, m3));
    const float L = wls[0][row] * __expf(m0 - Mv) + wls[1][row] * __expf(m1 - Mv) +
                    wls[2][row] * __expf(m2 - Mv) + wls[3][row] * __expf(m3 - Mv);
    M[rr] = Mv;
    inv[rr] = 1.f / L;
  }

  // ---- pass 2: recompute scores, emit P (fp32 global + bf16 ptile), PV ----
  f32x4 accO[4];
#pragma unroll
  for (int u = 0; u < 4; ++u) {
    accO[u][0] = 0.f; accO[u][1] = 0.f; accO[u][2] = 0.f; accO[u][3] = 0.f;
  }
  float* arow0 = attnO + ((size_t)bh * SSEQ + q0) * SSEQ;  // + row*SSEQ + col

  for (int st = 0; st < 16; ++st) {
    const int n0 = kbase + st * 32;
    const short* kr0 = Kh + (size_t)(n0 + lr) * D_MODEL;
    const short* kr1 = Kh + (size_t)(n0 + 16 + lr) * D_MODEL;
    const bf16x8 ka0 = *(const bf16x8*)&kr0[g * 8];
    const bf16x8 ka1 = *(const bf16x8*)&kr0[32 + g * 8];
    const bf16x8 kb0 = *(const bf16x8*)&kr1[g * 8];
    const bf16x8 kb1 = *(const bf16x8*)&kr1[32 + g * 8];
    bf16x8 bv[4];
#pragma unroll
    for (int u = 0; u < 4; ++u)
      bv[u] = *(const bf16x8*)&Vh[(size_t)(u * 16 + lr) * SSEQ + n0 + g * 8];

    f32x4 sA, sB;
    sA[0] = 0.f; sA[1] = 0.f; sA[2] = 0.f; sA[3] = 0.f;
    sB[0] = 0.f; sB[1] = 0.f; sB[2] = 0.f; sB[3] = 0.f;
    sA = __builtin_amdgcn_mfma_f32_16x16x32_bf16(aq0, ka0, sA, 0, 0, 0);
    sA = __builtin_amdgcn_mfma_f32_16x16x32_bf16(aq1, ka1, sA, 0, 0, 0);
    sB = __builtin_amdgcn_mfma_f32_16x16x32_bf16(aq0, kb0, sB, 0, 0, 0);
    sB = __builtin_amdgcn_mfma_f32_16x16x32_bf16(aq1, kb1, sB, 0, 0, 0);

#pragma unroll
    for (int rr = 0; rr < 4; ++rr) {
      const int row = g * 4 + rr;
      const float pa = __expf(sA[rr] * 0.125f - M[rr]) * inv[rr];
      const float pb = __expf(sB[rr] * 0.125f - M[rr]) * inv[rr];
      arow0[(size_t)row * SSEQ + n0 + lr] = pa;        // coalesced across lr
      arow0[(size_t)row * SSEQ + n0 + 16 + lr] = pb;
      ptile[w][row][lr] = f2b(pa);
      ptile[w][row][16 + lr] = f2b(pb);
    }
    // A-frag: P[row=lr][k = g*8..+8] (wave-local; lgkmcnt wait, no barrier)
    const bf16x8 ap = *(const bf16x8*)&ptile[w][lr][g * 8];
#pragma unroll
    for (int u = 0; u < 4; ++u)
      accO[u] = __builtin_amdgcn_mfma_f32_16x16x32_bf16(ap, bv[u], accO[u], 0, 0, 0);
  }

  // ---- O reduce across the 4 waves' key ranges ----
#pragma unroll
  for (int u = 0; u < 4; ++u) red[w][u][l] = accO[u];
  __syncthreads();
  {
    f32x4 o = red[0][w][l];
    const f32x4 o1 = red[1][w][l], o2 = red[2][w][l], o3 = red[3][w][l];
    o[0] += o1[0] + o2[0] + o3[0];
    o[1] += o1[1] + o2[1] + o3[1];
    o[2] += o1[2] + o2[2] + o3[2];
    o[3] += o1[3] + o2[3] + o3[3];
#pragma unroll
    for (int rr = 0; rr < 4; ++rr) {
      const int qr = q0 + g * 4 + rr;
      ctx[((size_t)b * SSEQ + qr) * D_MODEL + h * HDIM + w * 16 + lr] =
          f2b(o[rr]);
    }
  }
}

// ---------------------------------------------------------------------------
extern "C" void kernel_launch(void* const* d_in, const int* in_sizes, int n_in,
                              void* d_out, int out_size, void* d_ws,
                              size_t ws_size, hipStream_t stream) {
  const float* qf  = (const float*)d_in[0];
  const float* kf  = (const float*)d_in[1];
  const float* vf  = (const float*)d_in[2];
  const float* wqf = (const float*)d_in[3];
  const float* wkf = (const float*)d_in[4];
  const float* wvf = (const float*)d_in[5];
  const float* wof = (const float*)d_in[6];

  float* out  = (float*)d_out;                       // [2,2048,1024]
  float* attn = out + (size_t)BB * SSEQ * D_MODEL;   // [2,16,2048,2048]

  const size_t NTOK = (size_t)BB * SSEQ;             // 4096
  const size_t XN = NTOK * D_MODEL;                  // 4M elements
  const size_t WN = (size_t)D_MODEL * D_MODEL;       // 1M elements

  short* qb  = (short*)d_ws;       // bf16 copies of inputs
  short* kb  = qb + XN;
  short* vb  = kb + XN;
  short* wqb = vb + XN;
  short* wkb = wqb + WN;
  short* wvb = wkb + WN;
  short* wob = wvb + WN;
  short* Qb  = wob + WN;           // projection results
  short* Kb  = Qb + XN;
  short* Vb  = Kb + XN;
  short* Vt  = Vb + XN;
  short* ctx = Vt + XN;            // total 72 MB

  // 0) fp32 -> bf16 conversions
  k_cvt<<<512, 256, 0, stream>>>(qf, qb, (int)(XN / 4));
  k_cvt<<<512, 256, 0, stream>>>(kf, kb, (int)(XN / 4));
  k_cvt<<<512, 256, 0, stream>>>(vf, vb, (int)(XN / 4));
  k_cvt<<<256, 256, 0, stream>>>(wqf, wqb, (int)(WN / 4));
  k_cvt<<<256, 256, 0, stream>>>(wkf, wkb, (int)(WN / 4));
  k_cvt<<<256, 256, 0, stream>>>(wvf, wvb, (int)(WN / 4));
  k_cvt<<<256, 256, 0, stream>>>(wof, wob, (int)(WN / 4));

  // 1) Q/K/V projections: x @ W^T
  k_gemm_qkv<<<dim3(D_MODEL / 128, NTOK / 128, 3), 256, 0, stream>>>(
      qb, kb, vb, wqb, wkb, wvb, Qb, Kb, Vb);
  // 2) V -> Vt[b,h,d,s]
  k_transpose_v<<<dim3(BB * NHEADS, SSEQ / 64), 256, 0, stream>>>(Vb, Vt);
  // 3) fused attention (+ attn_weights output, fp32)
  k_attn<<<4096, 256, 0, stream>>>(Qb, Kb, Vt, attn, ctx);
  // 4) output projection: ctx @ Wo^T (fp32 out)
  k_gemm_f32out<<<dim3(D_MODEL / 128, NTOK / 128), 256, 0, stream>>>(
      ctx, wob, out, D_MODEL, D_MODEL);
}

// Round 6
// 886.762 us; speedup vs baseline: 1.0781x; 1.0781x over previous
//
#include <hip/hip_runtime.h>
#include <stdint.h>
#include <stddef.h>

// Problem constants (B=2, S=2048, D_MODEL=1024, H=16, Dh=64).
// I/O dtype: fp32 (per reference). Internal compute: bf16 MFMA + fp32 accum.
#define D_MODEL 1024
#define NHEADS  16
#define HDIM    64
#define BB      2
#define SSEQ    2048

using bf16x8 = __attribute__((ext_vector_type(8))) short;  // 8 bf16 (4 VGPRs)
using f32x4  = __attribute__((ext_vector_type(4))) float;  // MFMA accumulator
using s16x4  = __attribute__((ext_vector_type(4))) short;

static __device__ __forceinline__ float b2f(short s) {
  union { float f; unsigned u; } v;
  v.u = ((unsigned)(unsigned short)s) << 16;
  return v.f;
}
static __device__ __forceinline__ short f2b(float f) {
  union { float f; unsigned u; } v;
  v.f = f;
  unsigned r = v.u + 0x7fffu + ((v.u >> 16) & 1u);  // RNE
  return (short)(r >> 16);
}
// round two fp32 to bf16: returns packed (lo=a, hi=b); outputs rounded fp32
static __device__ __forceinline__ unsigned rnd2(float a, float b, float* fa,
                                                float* fb) {
  union { float f; unsigned u; } x, y;
  x.f = a; y.f = b;
  const unsigned ra = (x.u + 0x7fffu + ((x.u >> 16) & 1u)) & 0xffff0000u;
  const unsigned rb = (y.u + 0x7fffu + ((y.u >> 16) & 1u)) & 0xffff0000u;
  x.u = ra; y.u = rb;
  *fa = x.f; *fb = y.f;
  return (ra >> 16) | rb;
}
static __device__ __forceinline__ float unlo(unsigned u) {
  union { float f; unsigned v; } x; x.v = u << 16; return x.f;
}
static __device__ __forceinline__ float unhi(unsigned u) {
  union { float f; unsigned v; } x; x.v = u & 0xffff0000u; return x.f;
}

// async global->LDS, 16B per lane; LDS dest = wave-uniform base + lane*16
static __device__ __forceinline__ void gload16(const void* g, void* l) {
  __builtin_amdgcn_global_load_lds(
      (const __attribute__((address_space(1))) unsigned int*)g,
      (__attribute__((address_space(3))) unsigned int*)l, 16, 0, 0);
}

// ---------------------------------------------------------------------------
// fp32 -> bf16 conversion (grid-stride, float4 loads, 8B stores)
// ---------------------------------------------------------------------------
__global__ __launch_bounds__(256) void k_cvt(const float* __restrict__ src,
                                             short* __restrict__ dst, int n4) {
  int i = blockIdx.x * blockDim.x + threadIdx.x;
  const int stride = gridDim.x * blockDim.x;
  for (; i < n4; i += stride) {
    const float4 v = ((const float4*)src)[i];
    s16x4 o;
    o[0] = f2b(v.x); o[1] = f2b(v.y); o[2] = f2b(v.z); o[3] = f2b(v.w);
    ((s16x4*)dst)[i] = o;
  }
}

// ---------------------------------------------------------------------------
// C[M,N] = A[M,K] @ W[N,K]^T   (bf16 in, fp32 accum; out bf16 or fp32)
// 128x128 tile, BK=32, 256 threads (4 waves in 2x2), m97-style staging.
// ---------------------------------------------------------------------------
template <bool F32OUT>
static __device__ __forceinline__ void gemm_bt_dev(
    const short* __restrict__ A, const short* __restrict__ W, void* __restrict__ Cv,
    int N, int K) {
  __shared__ short sA[128 * 32];
  __shared__ short sB[128 * 32];

  const int t  = threadIdx.x;
  const int l  = t & 63;
  const int w  = t >> 6;
  const int wm = w >> 1, wn = w & 1;
  const int g  = l >> 4, lr = l & 15;
  const int m0 = blockIdx.y * 128;
  const int n0 = blockIdx.x * 128;

  f32x4 acc[4][4];
#pragma unroll
  for (int i = 0; i < 4; ++i)
#pragma unroll
    for (int j = 0; j < 4; ++j) {
      acc[i][j][0] = 0.f; acc[i][j][1] = 0.f;
      acc[i][j][2] = 0.f; acc[i][j][3] = 0.f;
    }

  const int r0 = t >> 2;
  const int c0 = (t & 3) * 8;
  const short* ga0 = A + (size_t)(m0 + r0) * K + c0;
  const short* ga1 = A + (size_t)(m0 + 64 + r0) * K + c0;
  const short* gb0 = W + (size_t)(n0 + r0) * K + c0;
  const short* gb1 = W + (size_t)(n0 + 64 + r0) * K + c0;
  short* la0 = &sA[(t & ~63) * 8];
  short* la1 = la0 + 256 * 8;
  short* lb0 = &sB[(t & ~63) * 8];
  short* lb1 = lb0 + 256 * 8;

  for (int k0 = 0; k0 < K; k0 += 32) {
    __syncthreads();  // WAR: previous iter's fragment reads done
    gload16(ga0 + k0, la0);
    gload16(ga1 + k0, la1);
    gload16(gb0 + k0, lb0);
    gload16(gb1 + k0, lb1);
    __syncthreads();  // drains vmcnt: staged tile visible

    bf16x8 af[4], bfr[4];
#pragma unroll
    for (int i = 0; i < 4; ++i)
      af[i] = *(const bf16x8*)&sA[(wm * 64 + i * 16 + lr) * 32 + g * 8];
#pragma unroll
    for (int i = 0; i < 4; ++i)
      bfr[i] = *(const bf16x8*)&sB[(wn * 64 + i * 16 + lr) * 32 + g * 8];
#pragma unroll
    for (int i = 0; i < 4; ++i)
#pragma unroll
      for (int j = 0; j < 4; ++j)
        acc[i][j] = __builtin_amdgcn_mfma_f32_16x16x32_bf16(af[i], bfr[j],
                                                            acc[i][j], 0, 0, 0);
  }

  // epilogue: D row=(lane>>4)*4+reg, col=lane&15  [verified C/D layout]
#pragma unroll
  for (int i = 0; i < 4; ++i)
#pragma unroll
    for (int j = 0; j < 4; ++j)
#pragma unroll
      for (int rr = 0; rr < 4; ++rr) {
        const int row = m0 + wm * 64 + i * 16 + g * 4 + rr;
        const int col = n0 + wn * 64 + j * 16 + lr;
        if (F32OUT)
          ((float*)Cv)[(size_t)row * N + col] = acc[i][j][rr];
        else
          ((short*)Cv)[(size_t)row * N + col] = f2b(acc[i][j][rr]);
      }
}

__global__ __launch_bounds__(256) void k_gemm_f32out(
    const short* __restrict__ A, const short* __restrict__ W,
    float* __restrict__ C, int N, int K) {
  gemm_bt_dev<true>(A, W, C, N, K);
}

__global__ __launch_bounds__(256) void k_gemm_qkv(
    const short* __restrict__ q, const short* __restrict__ k,
    const short* __restrict__ v, const short* __restrict__ wq,
    const short* __restrict__ wk, const short* __restrict__ wv,
    short* __restrict__ Qb, short* __restrict__ Kb, short* __restrict__ Vb) {
  const short *A, *W;
  short* C;
  if (blockIdx.z == 0)      { A = q; W = wq; C = Qb; }
  else if (blockIdx.z == 1) { A = k; W = wk; C = Kb; }
  else                      { A = v; W = wv; C = Vb; }
  gemm_bt_dev<false>(A, W, C, D_MODEL, D_MODEL);
}

// ---------------------------------------------------------------------------
// V[b,s,h*64+d] -> Vt[b,h,d,s]  (64x64 LDS tiles, pad 66 to spread banks)
// ---------------------------------------------------------------------------
__global__ __launch_bounds__(256) void k_transpose_v(
    const short* __restrict__ Vb, short* __restrict__ Vt) {
  __shared__ short tile[64][66];
  const int bh = blockIdx.x;            // b*16+h
  const int b = bh >> 4, h = bh & 15;
  const int s0 = blockIdx.y * 64;
  const int t = threadIdx.x;
#pragma unroll
  for (int i = 0; i < 16; ++i) {
    int e = t + i * 256;
    int si = e >> 6, dj = e & 63;
    tile[si][dj] = Vb[((size_t)b * SSEQ + s0 + si) * D_MODEL + h * HDIM + dj];
  }
  __syncthreads();
#pragma unroll
  for (int i = 0; i < 16; ++i) {
    int e = t + i * 256;
    int dj = e >> 6, si = e & 63;
    Vt[((size_t)bh * HDIM + dj) * SSEQ + s0 + si] = tile[si][dj];
  }
}

// ---------------------------------------------------------------------------
// Fused attention, round-6: two-pass with SWAPPED QK^T and S-in-registers.
// r5 evidence: kernel BW == write-stream rate (1.42 TB/s), all pipes idle ->
// stores gate loads via in-order vmcnt retirement. Fixes:
//  - mfma(K,Q) instead of mfma(Q,K): lane holds 4 CONSECUTIVE keys of its
//    q-row -> float4 P-stores (1 instr = dense 1 KB), 2-level shfl combine,
//    scalar per-lane M/inv, conflict-free un-swizzled ptile.
//  - scores kept as packed bf16 in 64 VGPRs (full unroll, const indices):
//    pass 2 has NO K loads / NO QK MFMA -> store stream can't collide with
//    a K-load chain.
//  - pass 2 issues V loads BEFORE stores each step: V-wait = vmcnt(#stores),
//    resolved without draining the store queue (in-order retirement).
// 4 waves, wave owns 512 keys; O cross-wave reduce via 16 KB LDS.
// LDS 22 KB; VGPR ~150 expected (watch counter for spill).
// ---------------------------------------------------------------------------
__global__ __launch_bounds__(256) void k_attn(
    const short* __restrict__ Qb, const short* __restrict__ Kb,
    const short* __restrict__ Vt, float* __restrict__ attnO,
    short* __restrict__ ctx) {
  __shared__ __attribute__((aligned(16))) short ptile[4][16][40];  // 5 KB
  __shared__ float wmx[4][16];                                     // 256 B
  __shared__ float wls[4][16];                                     // 256 B
  __shared__ f32x4 red[4][4][64];                                  // 16 KB

  const int t = threadIdx.x;
  const int l = t & 63, w = t >> 6;   // 4 waves
  const int g = l >> 4, lr = l & 15;
  // XCD-chunked bijective swizzle (4096 = 8*512)
  const int orig = blockIdx.x;
  const int id = (orig & 7) * 512 + (orig >> 3);
  const int q0 = (id & 127) * 16;
  const int bh = id >> 7;             // 0..31
  const int b = bh >> 4, h = bh & 15;

  // Q fragment (B-operand now): lane holds Q[q0+lr][g*8 .. +8] (+32 half 2)
  const size_t qoff = ((size_t)b * SSEQ + q0 + lr) * D_MODEL + h * HDIM;
  const bf16x8 aq0 = *(const bf16x8*)&Qb[qoff + g * 8];
  const bf16x8 aq1 = *(const bf16x8*)&Qb[qoff + 32 + g * 8];

  const short* Kh = Kb + (size_t)b * SSEQ * D_MODEL + h * HDIM;
  const short* Vh = Vt + (size_t)bh * HDIM * SSEQ;
  const int kbase = w * 512;          // this wave's key range

  // ---- pass 1: swapped QK^T; online (m,l); pack S to bf16 in registers ----
  // D = mfma(K,Q): row=(l>>4)*4+reg = LOCAL KEY g*4+rr, col = l&15 = q-row lr.
  unsigned sreg[64];                  // 16 steps x 4 uints (8 bf16 scores)
  float pm = -1e30f, pl = 0.f;
#pragma unroll
  for (int st = 0; st < 16; ++st) {
    const int n0 = kbase + st * 32;
    const short* kr0 = Kh + (size_t)(n0 + lr) * D_MODEL;
    const short* kr1 = Kh + (size_t)(n0 + 16 + lr) * D_MODEL;
    const bf16x8 ka0 = *(const bf16x8*)&kr0[g * 8];
    const bf16x8 ka1 = *(const bf16x8*)&kr0[32 + g * 8];
    const bf16x8 kb0 = *(const bf16x8*)&kr1[g * 8];
    const bf16x8 kb1 = *(const bf16x8*)&kr1[32 + g * 8];
    f32x4 sA, sB;
    sA[0] = 0.f; sA[1] = 0.f; sA[2] = 0.f; sA[3] = 0.f;
    sB[0] = 0.f; sB[1] = 0.f; sB[2] = 0.f; sB[3] = 0.f;
    sA = __builtin_amdgcn_mfma_f32_16x16x32_bf16(ka0, aq0, sA, 0, 0, 0);
    sA = __builtin_amdgcn_mfma_f32_16x16x32_bf16(ka1, aq1, sA, 0, 0, 0);
    sB = __builtin_amdgcn_mfma_f32_16x16x32_bf16(kb0, aq0, sB, 0, 0, 0);
    sB = __builtin_amdgcn_mfma_f32_16x16x32_bf16(kb1, aq1, sB, 0, 0, 0);
    // lane's 8 keys (row lr): n0+g*4+0..3 and n0+16+g*4+0..3
    float v0, v1, v2, v3, v4, v5, v6, v7;
    sreg[st * 4 + 0] = rnd2(sA[0] * 0.125f, sA[1] * 0.125f, &v0, &v1);
    sreg[st * 4 + 1] = rnd2(sA[2] * 0.125f, sA[3] * 0.125f, &v2, &v3);
    sreg[st * 4 + 2] = rnd2(sB[0] * 0.125f, sB[1] * 0.125f, &v4, &v5);
    sreg[st * 4 + 3] = rnd2(sB[2] * 0.125f, sB[3] * 0.125f, &v6, &v7);
    const float mx = fmaxf(fmaxf(fmaxf(v0, v1), fmaxf(v2, v3)),
                           fmaxf(fmaxf(v4, v5), fmaxf(v6, v7)));
    const float nm = fmaxf(pm, mx);
    const float s = __expf(v0 - nm) + __expf(v1 - nm) + __expf(v2 - nm) +
                    __expf(v3 - nm) + __expf(v4 - nm) + __expf(v5 - nm) +
                    __expf(v6 - nm) + __expf(v7 - nm);
    pl = pl * __expf(pm - nm) + s;
    pm = nm;
  }
  // combine across the 4 g-groups holding row lr (lanes differ in bits 4,5)
#pragma unroll
  for (int mask = 16; mask <= 32; mask <<= 1) {
    const float om = __shfl_xor(pm, mask, 64);
    const float ol = __shfl_xor(pl, mask, 64);
    const float nm = fmaxf(pm, om);
    pl = pl * __expf(pm - nm) + ol * __expf(om - nm);
    pm = nm;
  }
  if (l < 16) { wmx[w][lr] = pm; wls[w][lr] = pl; }
  __syncthreads();

  float M, inv;
  {
    const float m0 = wmx[0][lr], m1 = wmx[1][lr];
    const float m2 = wmx[2][lr], m3 = wmx[3][lr];
    M = fmaxf(fmaxf(m0, m1), fmaxf(m2, m3));
    const float L = wls[0][lr] * __expf(m0 - M) + wls[1][lr] * __expf(m1 - M) +
                    wls[2][lr] * __expf(m2 - M) + wls[3][lr] * __expf(m3 - M);
    inv = 1.f / L;
  }

  // ---- pass 2: emit P (float4 stores + bf16 ptile) and PV ----
  f32x4 accO[4];
#pragma unroll
  for (int u = 0; u < 4; ++u) {
    accO[u][0] = 0.f; accO[u][1] = 0.f; accO[u][2] = 0.f; accO[u][3] = 0.f;
  }
  float* arow = attnO + ((size_t)bh * SSEQ + q0 + lr) * SSEQ;  // row q0+lr

#pragma unroll
  for (int st = 0; st < 16; ++st) {
    const int n0 = kbase + st * 32;
    // V loads FIRST (oldest in vmcnt queue -> their wait skips store drain)
    const bf16x8 bv0 = *(const bf16x8*)&Vh[(size_t)(lr) * SSEQ + n0 + g * 8];
    const bf16x8 bv1 = *(const bf16x8*)&Vh[(size_t)(16 + lr) * SSEQ + n0 + g * 8];
    const bf16x8 bv2 = *(const bf16x8*)&Vh[(size_t)(32 + lr) * SSEQ + n0 + g * 8];
    const bf16x8 bv3 = *(const bf16x8*)&Vh[(size_t)(48 + lr) * SSEQ + n0 + g * 8];

    const unsigned u0 = sreg[st * 4 + 0], u1 = sreg[st * 4 + 1];
    const unsigned u2 = sreg[st * 4 + 2], u3 = sreg[st * 4 + 3];
    const float pa0 = __expf(unlo(u0) - M) * inv;
    const float pa1 = __expf(unhi(u0) - M) * inv;
    const float pa2 = __expf(unlo(u1) - M) * inv;
    const float pa3 = __expf(unhi(u1) - M) * inv;
    const float pa4 = __expf(unlo(u2) - M) * inv;
    const float pa5 = __expf(unhi(u2) - M) * inv;
    const float pa6 = __expf(unlo(u3) - M) * inv;
    const float pa7 = __expf(unhi(u3) - M) * inv;

    float4 s0, s1;
    s0.x = pa0; s0.y = pa1; s0.z = pa2; s0.w = pa3;
    s1.x = pa4; s1.y = pa5; s1.z = pa6; s1.w = pa7;
    // dense: 4 g-lanes x 16B = 64 B contiguous per q-row, x16 rows per instr
    *(float4*)(arow + n0 + g * 4) = s0;
    *(float4*)(arow + n0 + 16 + g * 4) = s1;

    s16x4 h0, h1;
    h0[0] = f2b(pa0); h0[1] = f2b(pa1); h0[2] = f2b(pa2); h0[3] = f2b(pa3);
    h1[0] = f2b(pa4); h1[1] = f2b(pa5); h1[2] = f2b(pa6); h1[3] = f2b(pa7);
    *(s16x4*)&ptile[w][lr][g * 4] = h0;
    *(s16x4*)&ptile[w][lr][16 + g * 4] = h1;
    // wave-local write->read (in-order DS + compiler lgkm wait; no barrier)
    const bf16x8 ap = *(const bf16x8*)&ptile[w][lr][g * 8];
    accO[0] = __builtin_amdgcn_mfma_f32_16x16x32_bf16(ap, bv0, accO[0], 0, 0, 0);
    accO[1] = __builtin_amdgcn_mfma_f32_16x16x32_bf16(ap, bv1, accO[1], 0, 0, 0);
    accO[2] = __builtin_amdgcn_mfma_f32_16x16x32_bf16(ap, bv2, accO[2], 0, 0, 0);
    accO[3] = __builtin_amdgcn_mfma_f32_16x16x32_bf16(ap, bv3, accO[3], 0, 0, 0);
  }

  // ---- O reduce across the 4 waves' key ranges ----
#pragma unroll
  for (int u = 0; u < 4; ++u) red[w][u][l] = accO[u];
  __syncthreads();
  {
    f32x4 o = red[0][w][l];
    const f32x4 o1 = red[1][w][l], o2 = red[2][w][l], o3 = red[3][w][l];
    o[0] += o1[0] + o2[0] + o3[0];
    o[1] += o1[1] + o2[1] + o3[1];
    o[2] += o1[2] + o2[2] + o3[2];
    o[3] += o1[3] + o2[3] + o3[3];
#pragma unroll
    for (int rr = 0; rr < 4; ++rr) {
      const int qr = q0 + g * 4 + rr;
      ctx[((size_t)b * SSEQ + qr) * D_MODEL + h * HDIM + w * 16 + lr] =
          f2b(o[rr]);
    }
  }
}

// ---------------------------------------------------------------------------
extern "C" void kernel_launch(void* const* d_in, const int* in_sizes, int n_in,
                              void* d_out, int out_size, void* d_ws,
                              size_t ws_size, hipStream_t stream) {
  const float* qf  = (const float*)d_in[0];
  const float* kf  = (const float*)d_in[1];
  const float* vf  = (const float*)d_in[2];
  const float* wqf = (const float*)d_in[3];
  const float* wkf = (const float*)d_in[4];
  const float* wvf = (const float*)d_in[5];
  const float* wof = (const float*)d_in[6];

  float* out  = (float*)d_out;                       // [2,2048,1024]
  float* attn = out + (size_t)BB * SSEQ * D_MODEL;   // [2,16,2048,2048]

  const size_t NTOK = (size_t)BB * SSEQ;             // 4096
  const size_t XN = NTOK * D_MODEL;                  // 4M elements
  const size_t WN = (size_t)D_MODEL * D_MODEL;       // 1M elements

  short* qb  = (short*)d_ws;       // bf16 copies of inputs
  short* kb  = qb + XN;
  short* vb  = kb + XN;
  short* wqb = vb + XN;
  short* wkb = wqb + WN;
  short* wvb = wkb + WN;
  short* wob = wvb + WN;
  short* Qb  = wob + WN;           // projection results
  short* Kb  = Qb + XN;
  short* Vb  = Kb + XN;
  short* Vt  = Vb + XN;
  short* ctx = Vt + XN;            // total 72 MB

  // 0) fp32 -> bf16 conversions
  k_cvt<<<512, 256, 0, stream>>>(qf, qb, (int)(XN / 4));
  k_cvt<<<512, 256, 0, stream>>>(kf, kb, (int)(XN / 4));
  k_cvt<<<512, 256, 0, stream>>>(vf, vb, (int)(XN / 4));
  k_cvt<<<256, 256, 0, stream>>>(wqf, wqb, (int)(WN / 4));
  k_cvt<<<256, 256, 0, stream>>>(wkf, wkb, (int)(WN / 4));
  k_cvt<<<256, 256, 0, stream>>>(wvf, wvb, (int)(WN / 4));
  k_cvt<<<256, 256, 0, stream>>>(wof, wob, (int)(WN / 4));

  // 1) Q/K/V projections: x @ W^T
  k_gemm_qkv<<<dim3(D_MODEL / 128, NTOK / 128, 3), 256, 0, stream>>>(
      qb, kb, vb, wqb, wkb, wvb, Qb, Kb, Vb);
  // 2) V -> Vt[b,h,d,s]
  k_transpose_v<<<dim3(BB * NHEADS, SSEQ / 64), 256, 0, stream>>>(Vb, Vt);
  // 3) fused attention (+ attn_weights output, fp32)
  k_attn<<<4096, 256, 0, stream>>>(Qb, Kb, Vt, attn, ctx);
  // 4) output projection: ctx @ Wo^T (fp32 out)
  k_gemm_f32out<<<dim3(D_MODEL / 128, NTOK / 128), 256, 0, stream>>>(
      ctx, wob, out, D_MODEL, D_MODEL);
}